// Round 13
// baseline (1712.042 us; speedup 1.0000x reference)
//
#include <hip/hip_runtime.h>
#include <hip/hip_bf16.h>
#include <math.h>

// ---------------------------------------------------------------------------
// Classifier_with_Augmentation — bf16 MFMA implicit-GEMM encoder, NHWC padded.
//  outputs (flat float32 in d_out):
//   labels 16x200 @0 | win_scores 16x7 @3200 | win_logits 112x200 @3312
//   indices 16x7 @25712 | all_scores 16x602 @25824 | coordinates 16x7x4 @35456
// ---------------------------------------------------------------------------

#define OFF_LAB 0
#define OFF_WSC 3200
#define OFF_LOG 3312
#define OFF_IDX 25712
#define OFF_ALL 25824
#define OFF_CRD 35456

#define BS 256

typedef __attribute__((ext_vector_type(8))) short short8;
typedef __attribute__((ext_vector_type(4))) float f32x4;

static inline int cdiv(int a, int b) { return (a + b - 1) / b; }

// ---- window geometry ------------------------------------------------------
__device__ __forceinline__ void win_decode(int w, int& rh, int& rw, int& r, int& c) {
  const int RH[6] = {4, 3, 5, 6, 5, 7};
  const int RW[6] = {4, 5, 3, 6, 7, 5};
  int rem = w;
#pragma unroll
  for (int i = 0; i < 6; ++i) {
    int nc = 15 - RW[i];
    int cnt = (15 - RH[i]) * nc;
    if (rem < cnt) { rh = RH[i]; rw = RW[i]; r = rem / nc; c = rem - (rem / nc) * nc; return; }
    rem -= cnt;
  }
  rh = 4; rw = 4; r = 0; c = 0;
}

__device__ __forceinline__ void win_to_box(int w, float* bb) {
  int rh, rw, r, c;
  win_decode(w, rh, rw, r, c);
  bb[0] = r * 32.f;
  bb[1] = c * 32.f;
  bb[2] = (r + rh) * 32.f - 1.f;
  bb[3] = (c + rw) * 32.f - 1.f;
}

// ---- window scores --------------------------------------------------------
__global__ void winscores_kernel(const float* __restrict__ att, float* __restrict__ s_all,
                                 float* __restrict__ out) {
  int idx = blockIdx.x * blockDim.x + threadIdx.x;
  if (idx >= 16 * 602) return;
  int b = idx / 602, w = idx - b * 602;
  int rh, rw, r, c;
  win_decode(w, rh, rw, r, c);
  const float* a = att + b * 196;
  float s = 0.f;
  for (int dr = 0; dr < rh; ++dr)
    for (int dc = 0; dc < rw; ++dc)
      s += a[(r + dr) * 14 + (c + dc)];
  float v = s / (float)(rh * rw);
  s_all[idx] = v;
  out[OFF_ALL + idx] = v;
}

// ---- NMS: one wave per (batch, group) -------------------------------------
__global__ void nms_kernel(const float* __restrict__ s_all, int* __restrict__ idx_i) {
  const int b = blockIdx.x, g = blockIdx.y;
  const int gs = g ? 361 : 0;
  const int cnt = g ? 241 : 361;
  const int nsel = g ? 3 : 4;
  const int obase = b * 7 + (g ? 4 : 0);
  __shared__ float sc[361];
  __shared__ float bx0[361], bx1[361], bx2[361], bx3[361];
  const int tid = threadIdx.x;
  for (int k = tid; k < cnt; k += 64) {
    sc[k] = s_all[b * 602 + gs + k];
    float bb[4];
    win_to_box(gs + k, bb);
    bx0[k] = bb[0]; bx1[k] = bb[1]; bx2[k] = bb[2]; bx3[k] = bb[3];
  }
  __syncthreads();
  for (int it = 0; it < nsel; ++it) {
    float bv = -INFINITY;
    int bi = 0x7fffffff;
    for (int k = tid; k < cnt; k += 64) {
      float v = sc[k];
      if (v > bv || (v == bv && k < bi)) { bv = v; bi = k; }
    }
#pragma unroll
    for (int off = 32; off > 0; off >>= 1) {
      float ov = __shfl_down(bv, off);
      int oi = __shfl_down(bi, off);
      if (ov > bv || (ov == bv && oi < bi)) { bv = ov; bi = oi; }
    }
    bi = __shfl(bi, 0);
    if (tid == 0) idx_i[obase + it] = gs + bi;
    float X0 = bx0[bi], X1 = bx1[bi], X2 = bx2[bi], X3 = bx3[bi];
    float a1 = (X2 - X0 + 1.f) * (X3 - X1 + 1.f);
    __syncthreads();
    for (int k = tid; k < cnt; k += 64) {
      float x0 = fmaxf(X0, bx0[k]);
      float y0 = fmaxf(X1, bx1[k]);
      float x1 = fminf(X2, bx2[k]);
      float y1 = fminf(X3, bx3[k]);
      float inter = fmaxf(x1 - x0 + 1.f, 0.f) * fmaxf(y1 - y0 + 1.f, 0.f);
      float a2 = (bx2[k] - bx0[k] + 1.f) * (bx3[k] - bx1[k] + 1.f);
      float iou = inter / (a1 + a2 - inter);
      if (iou > 0.25f) sc[k] = -INFINITY;
    }
    if (tid == 0) sc[bi] = -INFINITY;
    __syncthreads();
  }
}

// ---- gather ---------------------------------------------------------------
__global__ void gather_kernel(const int* __restrict__ idx_i, const float* __restrict__ s_all,
                              float* __restrict__ boxes, float* __restrict__ out) {
  int t = blockIdx.x * blockDim.x + threadIdx.x;
  if (t >= 112) return;
  int b = t / 7;
  int w = idx_i[t];
  out[OFF_IDX + t] = (float)w;
  out[OFF_WSC + t] = s_all[b * 602 + w];
  float bb[4];
  win_to_box(w, bb);
#pragma unroll
  for (int k = 0; k < 4; ++k) {
    boxes[t * 4 + k] = bb[k];
    out[OFF_CRD + t * 4 + k] = bb[k];
  }
}

// ---- bilinear crop-resize 448 -> 112 (fp32, exact) ------------------------
__global__ void crop_resize_kernel(const float* __restrict__ x, const float* __restrict__ boxes,
                                   float* __restrict__ wimgs) {
  int idx = blockIdx.x * blockDim.x + threadIdx.x;
  const int total = 112 * 3 * 112 * 112;
  if (idx >= total) return;
  int j = idx % 112;
  int i = (idx / 112) % 112;
  int ch = (idx / (112 * 112)) % 3;
  int bp = idx / (3 * 112 * 112);
  int b = bp / 7;
  const float* bx = boxes + bp * 4;
  float t_i = (float)i / 111.0f;
  float t_j = (float)j / 111.0f;
  float rs = bx[0] + (bx[2] - bx[0]) * t_i;
  float cs = bx[1] + (bx[3] - bx[1]) * t_j;
  float r0f = floorf(rs), c0f = floorf(cs);
  float wr = rs - r0f, wc = cs - c0f;
  int r0 = (int)r0f, c0 = (int)c0f;
  int r1 = min(r0 + 1, 447), c1 = min(c0 + 1, 447);
  const float* img = x + ((size_t)b * 3 + ch) * 448 * 448;
  float v00 = img[r0 * 448 + c0], v01 = img[r0 * 448 + c1];
  float v10 = img[r1 * 448 + c0], v11 = img[r1 * 448 + c1];
  float top = (1.f - wc) * v00 + wc * v01;
  float bot = (1.f - wc) * v10 + wc * v11;
  wimgs[idx] = (1.f - wr) * top + wr * bot;
}

// ---- zero fill (16B) ------------------------------------------------------
__global__ void zf8_kernel(uint4* __restrict__ p, int n16) {
  int idx = blockIdx.x * blockDim.x + threadIdx.x;
  if (idx < n16) p[idx] = make_uint4(0, 0, 0, 0);
}

// ---- weight packing: wpk[t][co][ci] bf16 from fp32 [co][ci][3][3] ---------
__global__ void packw_kernel(const float* __restrict__ w, __hip_bfloat16* __restrict__ dst,
                             int Cout, int Cin) {
  int idx = blockIdx.x * blockDim.x + threadIdx.x;
  int total = Cout * Cin * 9;
  if (idx >= total) return;
  int ci = idx % Cin;
  int rc = idx / Cin;
  int co = rc % Cout;
  int t = rc / Cout;
  dst[idx] = __float2bfloat16(w[((size_t)co * Cin + ci) * 9 + t]);
}

// ---- L0 weight packing: wpk0[co][32] --------------------------------------
__global__ void packw0_kernel(const float* __restrict__ w, __hip_bfloat16* __restrict__ dst) {
  int idx = blockIdx.x * blockDim.x + threadIdx.x;
  if (idx >= 64 * 32) return;
  int co = idx >> 5, k = idx & 31;
  float v = 0.f;
  if (k < 27) {
    int t = k / 3, c = k - t * 3;
    v = w[((size_t)co * 3 + c) * 9 + t];
  }
  dst[idx] = __float2bfloat16(v);
}

// ---- im2col for Cin=3 layers: A[m][32] bf16 -------------------------------
__global__ void im2col3_kernel(const float* __restrict__ x, __hip_bfloat16* __restrict__ A,
                               int N, int Hin, int Hout) {
  int m = blockIdx.x * blockDim.x + threadIdx.x;
  int total = N * Hout * Hout;
  if (m >= total) return;
  int n = m / (Hout * Hout);
  int rem = m - n * (Hout * Hout);
  int oh = rem / Hout, ow = rem - (rem / Hout) * Hout;
  const float* xb = x + (size_t)n * 3 * Hin * Hin;
  __hip_bfloat16* a = A + (size_t)m * 32;
#pragma unroll
  for (int kh = 0; kh < 3; ++kh) {
#pragma unroll
    for (int kw = 0; kw < 3; ++kw) {
      int ih = 2 * oh + kh, iw = 2 * ow + kw;
      bool ok = (ih < Hin) && (iw < Hin);
#pragma unroll
      for (int c = 0; c < 3; ++c) {
        float v = ok ? xb[(size_t)c * Hin * Hin + (size_t)ih * Hin + iw] : 0.f;
        a[(kh * 3 + kw) * 3 + c] = __float2bfloat16(v);
      }
    }
  }
#pragma unroll
  for (int k = 27; k < 32; ++k) a[k] = __float2bfloat16(0.f);
}

// ================= bf16 MFMA conv (implicit GEMM, NHWC padded) ==============
// 8 waves/block. WIDE (Cout>=128): 2 co-groups x 4 px-groups per block -> A
// fetched once for all 128 co. K-loop: taps-outer, q in PAIRS (full 128B line
// consumed while resident). blockIdx.z splits q-range (nqz kept even).
template <bool IM2COL, bool WIDE>
__global__ __launch_bounds__(512) void conv_mfma_kernel(
    const __hip_bfloat16* __restrict__ in, const __hip_bfloat16* __restrict__ wpk,
    const float* __restrict__ bias, __hip_bfloat16* __restrict__ outp,
    float* __restrict__ pbuf,
    int M, int Hout, int Wout, int Hp, int Wp, int Cin, int Cout, int pad,
    int Hop, int Wop) {
  const int l = threadIdx.x & 63;
  const int w = threadIdx.x >> 6;
  int px0, co0;
  if (WIDE) {
    px0 = blockIdx.y * 128 + (w & 3) * 32;
    co0 = blockIdx.x * 128 + (w >> 2) * 64;
  } else {
    px0 = blockIdx.y * 256 + w * 32;
    co0 = blockIdx.x * 64;
  }
  if (px0 >= M) return;
  const int half = l >> 4;
  const int lr = l & 15;
  const int HWo = Hout * Wout;

  int mA0 = px0 + lr;      if (mA0 >= M) mA0 = M - 1;
  int mA1 = px0 + 16 + lr; if (mA1 >= M) mA1 = M - 1;
  const __hip_bfloat16* pA0;
  const __hip_bfloat16* pA1;
  if (IM2COL) {
    pA0 = in + (size_t)mA0 * 32 + half * 8;
    pA1 = in + (size_t)mA1 * 32 + half * 8;
  } else {
    int n0 = mA0 / HWo, r0 = mA0 - n0 * HWo, oh0 = r0 / Wout, ow0 = r0 - (r0 / Wout) * Wout;
    int n1 = mA1 / HWo, r1 = mA1 - n1 * HWo, oh1 = r1 / Wout, ow1 = r1 - (r1 / Wout) * Wout;
    pA0 = in + (((size_t)n0 * Hp + (2 * oh0 - pad + 1)) * Wp + (2 * ow0 - pad + 1)) * Cin +
          half * 8;
    pA1 = in + (((size_t)n1 * Hp + (2 * oh1 - pad + 1)) * Wp + (2 * ow1 - pad + 1)) * Cin +
          half * 8;
  }
  const __hip_bfloat16* pB = wpk + (size_t)(co0 + lr) * Cin + half * 8;
  const size_t sCo = (size_t)Cout * Cin;

  f32x4 acc[2][4];
#pragma unroll
  for (int ms = 0; ms < 2; ++ms)
#pragma unroll
    for (int s = 0; s < 4; ++s) acc[ms][s] = (f32x4){0.f, 0.f, 0.f, 0.f};

  const int nq = Cin >> 5;
  const int nqz = nq / gridDim.z;
  const int qlo = blockIdx.z * nqz;
  const int qhi = qlo + nqz;
  if (IM2COL) {
    for (int q = qlo; q < qhi; ++q) {
      short8 a0 = *(const short8*)(pA0);
      short8 a1 = *(const short8*)(pA1);
#pragma unroll
      for (int s = 0; s < 4; ++s) {
        short8 b = *(const short8*)(pB + (size_t)s * 16 * Cin);
        acc[0][s] = __builtin_amdgcn_mfma_f32_16x16x32_bf16(a0, b, acc[0][s], 0, 0, 0);
        acc[1][s] = __builtin_amdgcn_mfma_f32_16x16x32_bf16(a1, b, acc[1][s], 0, 0, 0);
      }
    }
  } else {
    // q in pairs (nqz even for all non-im2col layers/z-splits)
    for (int q = qlo; q < qhi; q += 2) {
      const int qa = q << 5, qb32 = qa + 32;
#pragma unroll
      for (int kh = 0; kh < 3; ++kh) {
#pragma unroll
        for (int kw = 0; kw < 3; ++kw) {
          const int dA = (kh * Wp + kw) * Cin;
          short8 a00 = *(const short8*)(pA0 + dA + qa);
          short8 a01 = *(const short8*)(pA0 + dA + qb32);
          short8 a10 = *(const short8*)(pA1 + dA + qa);
          short8 a11 = *(const short8*)(pA1 + dA + qb32);
          const __hip_bfloat16* qw = pB + (size_t)(kh * 3 + kw) * sCo;
#pragma unroll
          for (int s = 0; s < 4; ++s) {
            short8 b0 = *(const short8*)(qw + (size_t)s * 16 * Cin + qa);
            short8 b1 = *(const short8*)(qw + (size_t)s * 16 * Cin + qb32);
            acc[0][s] = __builtin_amdgcn_mfma_f32_16x16x32_bf16(a00, b0, acc[0][s], 0, 0, 0);
            acc[0][s] = __builtin_amdgcn_mfma_f32_16x16x32_bf16(a01, b1, acc[0][s], 0, 0, 0);
            acc[1][s] = __builtin_amdgcn_mfma_f32_16x16x32_bf16(a10, b0, acc[1][s], 0, 0, 0);
            acc[1][s] = __builtin_amdgcn_mfma_f32_16x16x32_bf16(a11, b1, acc[1][s], 0, 0, 0);
          }
        }
      }
    }
  }

  if (gridDim.z == 1) {
    float bj0 = bias[co0 + lr];
    float bj1 = bias[co0 + 16 + lr];
    float bj2 = bias[co0 + 32 + lr];
    float bj3 = bias[co0 + 48 + lr];
#pragma unroll
    for (int ms = 0; ms < 2; ++ms) {
#pragma unroll
      for (int r = 0; r < 4; ++r) {
        int m = px0 + ms * 16 + half * 4 + r;
        if (m >= M) continue;
        int n = m / HWo, rem = m - n * HWo;
        int oh = rem / Wout, ow = rem - (rem / Wout) * Wout;
        __hip_bfloat16* ob =
            outp + (((size_t)n * Hop + oh + 1) * Wop + (ow + 1)) * Cout + co0 + lr;
        ob[0] = __float2bfloat16(fmaxf(acc[ms][0][r] + bj0, 0.f));
        ob[16] = __float2bfloat16(fmaxf(acc[ms][1][r] + bj1, 0.f));
        ob[32] = __float2bfloat16(fmaxf(acc[ms][2][r] + bj2, 0.f));
        ob[48] = __float2bfloat16(fmaxf(acc[ms][3][r] + bj3, 0.f));
      }
    }
  } else {
    float* pz = pbuf + (size_t)blockIdx.z * M * Cout;
#pragma unroll
    for (int ms = 0; ms < 2; ++ms) {
#pragma unroll
      for (int r = 0; r < 4; ++r) {
        int m = px0 + ms * 16 + half * 4 + r;
        if (m >= M) continue;
        float* pm = pz + (size_t)m * Cout + co0 + lr;
        pm[0] = acc[ms][0][r];
        pm[16] = acc[ms][1][r];
        pm[32] = acc[ms][2][r];
        pm[48] = acc[ms][3][r];
      }
    }
  }
}

// ---- reduce z partials + bias + relu -> padded NHWC bf16 ------------------
__global__ void reduce_nhwc_kernel(const float* __restrict__ pbuf, const float* __restrict__ bias,
                                   __hip_bfloat16* __restrict__ outp, int M, int Cout, int nz,
                                   int Hout, int Wout, int Hop, int Wop) {
  int idx = blockIdx.x * blockDim.x + threadIdx.x;
  if (idx >= M * Cout) return;
  int m = idx / Cout, co = idx - m * Cout;
  float s = 0.f;
  for (int z = 0; z < nz; ++z) s += pbuf[(size_t)z * M * Cout + idx];
  s = fmaxf(s + bias[co], 0.f);
  int HWo = Hout * Wout;
  int n = m / HWo, rem = m - n * HWo;
  int oh = rem / Wout, ow = rem - (rem / Wout) * Wout;
  outp[(((size_t)n * Hop + oh + 1) * Wop + (ow + 1)) * Cout + co] = __float2bfloat16(s);
}

// ---- mean pool over NHWC padded interior ----------------------------------
__global__ void avgpool_nhwc_kernel(const __hip_bfloat16* __restrict__ feat,
                                    float* __restrict__ pooled, int Nimg, int H, int Hp, int C) {
  int idx = blockIdx.x * blockDim.x + threadIdx.x;
  if (idx >= Nimg * C) return;
  int n = idx / C, c = idx - n * C;
  float s = 0.f;
  for (int h = 1; h <= H; ++h)
    for (int ww = 1; ww <= H; ++ww)
      s += __bfloat162float(feat[(((size_t)n * Hp + h) * Hp + ww) * C + c]);
  pooled[idx] = s / (float)(H * H);
}

// ---- head GEMM (fp32) -----------------------------------------------------
__global__ void head_kernel(const float* __restrict__ pooled, const float* __restrict__ hw,
                            const float* __restrict__ hb, float* __restrict__ outp, int M) {
  int idx = blockIdx.x * blockDim.x + threadIdx.x;
  if (idx >= M * 200) return;
  int m = idx / 200, c = idx - m * 200;
  float acc = hb[c];
  const float* pm = pooled + m * 512;
  for (int k = 0; k < 512; ++k) acc = fmaf(pm[k], hw[k * 200 + c], acc);
  outp[idx] = acc;
}

// ---------------------------------------------------------------------------
static void launch_conv(bool im2col, const __hip_bfloat16* in, const __hip_bfloat16* wpk,
                        const float* bv, __hip_bfloat16* dst, float* pbuf, int nz, int M,
                        int Hout, int Hp, int Cin, int Cout, int pad, int Hop, hipStream_t s) {
  if (im2col) {
    dim3 grid(Cout / 64, cdiv(M, 256), nz);
    conv_mfma_kernel<true, false><<<grid, 512, 0, s>>>(in, wpk, bv, dst, pbuf, M, Hout, Hout, Hp,
                                                       Hp, Cin, Cout, pad, Hop, Hop);
  } else {
    dim3 grid(Cout / 128, cdiv(M, 128), nz);  // all non-im2col layers have Cout>=128
    conv_mfma_kernel<false, true><<<grid, 512, 0, s>>>(in, wpk, bv, dst, pbuf, M, Hout, Hout, Hp,
                                                       Hp, Cin, Cout, pad, Hop, Hop);
  }
  if (nz > 1)
    reduce_nhwc_kernel<<<cdiv(M * Cout, BS), BS, 0, s>>>(pbuf, bv, dst, M, Cout, nz, Hout, Hout,
                                                         Hop, Hop);
}

static void zf(__hip_bfloat16* p, size_t n, hipStream_t s) {
  zf8_kernel<<<cdiv((int)(n / 8), BS), BS, 0, s>>>((uint4*)p, (int)(n / 8));
}

extern "C" void kernel_launch(void* const* d_in, const int* in_sizes, int n_in,
                              void* d_out, int out_size, void* d_ws, size_t ws_size,
                              hipStream_t stream) {
  const float* x = (const float*)d_in[0];
  const float* att = (const float*)d_in[1];
  const float* W[5] = {(const float*)d_in[2], (const float*)d_in[4], (const float*)d_in[6],
                       (const float*)d_in[8], (const float*)d_in[10]};
  const float* Bv[5] = {(const float*)d_in[3], (const float*)d_in[5], (const float*)d_in[7],
                        (const float*)d_in[9], (const float*)d_in[11]};
  const float* head_w = (const float*)d_in[12];
  const float* head_b = (const float*)d_in[13];
  float* out = (float*)d_out;
  float* ws = (float*)d_ws;

  // ---- workspace (~135MB) ----
  size_t o = 0;
  float* s_all = ws + o;  o += 16 * 602;
  int* idx_i = (int*)(ws + o); o += 112;
  float* boxes = ws + o;  o += 112 * 4;
  float* pooled = ws + o; o += (size_t)112 * 512;
  float* wimgs = ws + o;  o += (size_t)112 * 3 * 112 * 112;
  __hip_bfloat16* hbb = (__hip_bfloat16*)(ws + o);
  size_t h = 0;
  __hip_bfloat16* wpk0 = hbb + h; h += 64 * 32;
  __hip_bfloat16* wpk1 = hbb + h; h += (size_t)9 * 128 * 64;
  __hip_bfloat16* wpk2 = hbb + h; h += (size_t)9 * 256 * 128;
  __hip_bfloat16* wpk3 = hbb + h; h += (size_t)9 * 512 * 256;
  __hip_bfloat16* wpk4 = hbb + h; h += (size_t)9 * 512 * 512;
  __hip_bfloat16* A_L0 = hbb + h; h += (size_t)200704 * 32;          // 6.42M el
  __hip_bfloat16* fL3c = A_L0;                                        // alias: crop-L3 out
  __hip_bfloat16* bufA = hbb + h; h += (size_t)4 * 226 * 226 * 64;   // 13.08M el
  float* pK = (float*)bufA;                                           // alias: split-K partials
  __hip_bfloat16* bufB = hbb + h; h += (size_t)4 * 114 * 114 * 128;  // 6.65M el
  __hip_bfloat16* bufC16 = hbb + h; h += (size_t)16 * 58 * 58 * 256; // 13.78M el
  __hip_bfloat16* fL3b = hbb + h; h += (size_t)16 * 30 * 30 * 512;   // 7.37M el
  __hip_bfloat16* featB = hbb + h; h += (size_t)16 * 16 * 16 * 512;  // 2.10M el
  __hip_bfloat16* featC = hbb + h; h += (size_t)112 * 6 * 6 * 512;   // 2.06M el

  // ---- proposal path (fp32, exact) ----
  winscores_kernel<<<cdiv(16 * 602, BS), BS, 0, stream>>>(att, s_all, out);
  nms_kernel<<<dim3(16, 2), 64, 0, stream>>>(s_all, idx_i);
  gather_kernel<<<1, 128, 0, stream>>>(idx_i, s_all, boxes, out);
  crop_resize_kernel<<<cdiv(112 * 3 * 112 * 112, BS), BS, 0, stream>>>(x, boxes, wimgs);

  // ---- pack weights ----
  packw0_kernel<<<cdiv(64 * 32, BS), BS, 0, stream>>>(W[0], wpk0);
  packw_kernel<<<cdiv(9 * 128 * 64, BS), BS, 0, stream>>>(W[1], wpk1, 128, 64);
  packw_kernel<<<cdiv(9 * 256 * 128, BS), BS, 0, stream>>>(W[2], wpk2, 256, 128);
  packw_kernel<<<cdiv(9 * 512 * 256, BS), BS, 0, stream>>>(W[3], wpk3, 512, 256);
  packw_kernel<<<cdiv(9 * 512 * 512, BS), BS, 0, stream>>>(W[4], wpk4, 512, 512);

  // ---- big encoder: L0-L2 in 4-image chunks; L3, L4 over all 16 ----
  zf(bufA, (size_t)4 * 226 * 226 * 64, stream);
  zf(bufB, (size_t)4 * 114 * 114 * 128, stream);
  zf(bufC16, (size_t)16 * 58 * 58 * 256, stream);
  zf(fL3b, (size_t)16 * 30 * 30 * 512, stream);
  zf(featB, (size_t)16 * 16 * 16 * 512, stream);
  for (int chunk = 0; chunk < 4; ++chunk) {
    int n0 = chunk * 4;
    im2col3_kernel<<<cdiv(200704, BS), BS, 0, stream>>>(x + (size_t)n0 * 3 * 448 * 448, A_L0, 4,
                                                        448, 224);
    launch_conv(true, A_L0, wpk0, Bv[0], bufA, nullptr, 1, 200704, 224, 0, 32, 64, 0, 226,
                stream);
    launch_conv(false, bufA, wpk1, Bv[1], bufB, nullptr, 1, 50176, 112, 226, 64, 128, 0, 114,
                stream);
    launch_conv(false, bufB, wpk2, Bv[2], bufC16 + (size_t)n0 * 58 * 58 * 256, nullptr, 1, 12544,
                56, 114, 128, 256, 0, 58, stream);
  }
  launch_conv(false, bufC16, wpk3, Bv[3], fL3b, nullptr, 1, 12544, 28, 58, 256, 512, 0, 30,
              stream);
  launch_conv(false, fL3b, wpk4, Bv[4], featB, pK, 4, 3136, 14, 30, 512, 512, 0, 16, stream);
  avgpool_nhwc_kernel<<<cdiv(16 * 512, BS), BS, 0, stream>>>(featB, pooled, 16, 14, 16, 512);
  head_kernel<<<cdiv(16 * 200, BS), BS, 0, stream>>>(pooled, head_w, head_b, out + OFF_LAB, 16);

  // ---- crop encoder: L0-L2 in 56-crop chunks; L3, L4 over all 112 ----
  zf(bufA, (size_t)4 * 226 * 226 * 64, stream);
  zf(bufB, (size_t)4 * 114 * 114 * 128, stream);
  zf(bufC16, (size_t)16 * 58 * 58 * 256, stream);
  zf(featC, (size_t)112 * 6 * 6 * 512, stream);
  for (int chunk = 0; chunk < 2; ++chunk) {
    int c0 = chunk * 56;
    im2col3_kernel<<<cdiv(175616, BS), BS, 0, stream>>>(wimgs + (size_t)c0 * 3 * 112 * 112, A_L0,
                                                        56, 112, 56);
    launch_conv(true, A_L0, wpk0, Bv[0], bufA, nullptr, 1, 175616, 56, 0, 32, 64, 0, 58, stream);
    launch_conv(false, bufA, wpk1, Bv[1], bufB, nullptr, 1, 43904, 28, 58, 64, 128, 0, 30,
                stream);
    launch_conv(false, bufB, wpk2, Bv[2], bufC16 + (size_t)c0 * 16 * 16 * 256, nullptr, 1, 10976,
                14, 30, 128, 256, 0, 16, stream);
  }
  // crop-L3 all-112 (z=2, nqz=4 even): fL3c aliases A_L0 (dead after last im2col)
  zf(fL3c, (size_t)112 * 9 * 9 * 512, stream);
  launch_conv(false, bufC16, wpk3, Bv[3], fL3c, pK, 2, 5488, 7, 16, 256, 512, 0, 9, stream);
  // crop-L4 all-112 (z=4, nqz=4 even)
  launch_conv(false, fL3c, wpk4, Bv[4], featC, pK, 4, 1792, 4, 9, 512, 512, 1, 6, stream);
  avgpool_nhwc_kernel<<<cdiv(112 * 512, BS), BS, 0, stream>>>(featC, pooled, 112, 4, 6, 512);
  head_kernel<<<cdiv(112 * 200, BS), BS, 0, stream>>>(pooled, head_w, head_b, out + OFF_LOG, 112);
}

// Round 14
// 1676.394 us; speedup vs baseline: 1.0213x; 1.0213x over previous
//
#include <hip/hip_runtime.h>
#include <hip/hip_bf16.h>
#include <math.h>

// ---------------------------------------------------------------------------
// Classifier_with_Augmentation — bf16 MFMA implicit-GEMM encoder, NHWC padded.
//  outputs (flat float32 in d_out):
//   labels 16x200 @0 | win_scores 16x7 @3200 | win_logits 112x200 @3312
//   indices 16x7 @25712 | all_scores 16x602 @25824 | coordinates 16x7x4 @35456
// ---------------------------------------------------------------------------

#define OFF_LAB 0
#define OFF_WSC 3200
#define OFF_LOG 3312
#define OFF_IDX 25712
#define OFF_ALL 25824
#define OFF_CRD 35456

#define BS 256

typedef __attribute__((ext_vector_type(8))) short short8;
typedef __attribute__((ext_vector_type(4))) float f32x4;

static inline int cdiv(int a, int b) { return (a + b - 1) / b; }

// ---- window geometry ------------------------------------------------------
__device__ __forceinline__ void win_decode(int w, int& rh, int& rw, int& r, int& c) {
  const int RH[6] = {4, 3, 5, 6, 5, 7};
  const int RW[6] = {4, 5, 3, 6, 7, 5};
  int rem = w;
#pragma unroll
  for (int i = 0; i < 6; ++i) {
    int nc = 15 - RW[i];
    int cnt = (15 - RH[i]) * nc;
    if (rem < cnt) { rh = RH[i]; rw = RW[i]; r = rem / nc; c = rem - (rem / nc) * nc; return; }
    rem -= cnt;
  }
  rh = 4; rw = 4; r = 0; c = 0;
}

__device__ __forceinline__ void win_to_box(int w, float* bb) {
  int rh, rw, r, c;
  win_decode(w, rh, rw, r, c);
  bb[0] = r * 32.f;
  bb[1] = c * 32.f;
  bb[2] = (r + rh) * 32.f - 1.f;
  bb[3] = (c + rw) * 32.f - 1.f;
}

// ---- window scores --------------------------------------------------------
__global__ void winscores_kernel(const float* __restrict__ att, float* __restrict__ s_all,
                                 float* __restrict__ out) {
  int idx = blockIdx.x * blockDim.x + threadIdx.x;
  if (idx >= 16 * 602) return;
  int b = idx / 602, w = idx - b * 602;
  int rh, rw, r, c;
  win_decode(w, rh, rw, r, c);
  const float* a = att + b * 196;
  float s = 0.f;
  for (int dr = 0; dr < rh; ++dr)
    for (int dc = 0; dc < rw; ++dc)
      s += a[(r + dr) * 14 + (c + dc)];
  float v = s / (float)(rh * rw);
  s_all[idx] = v;
  out[OFF_ALL + idx] = v;
}

// ---- NMS: one wave per (batch, group) -------------------------------------
__global__ void nms_kernel(const float* __restrict__ s_all, int* __restrict__ idx_i) {
  const int b = blockIdx.x, g = blockIdx.y;
  const int gs = g ? 361 : 0;
  const int cnt = g ? 241 : 361;
  const int nsel = g ? 3 : 4;
  const int obase = b * 7 + (g ? 4 : 0);
  __shared__ float sc[361];
  __shared__ float bx0[361], bx1[361], bx2[361], bx3[361];
  const int tid = threadIdx.x;
  for (int k = tid; k < cnt; k += 64) {
    sc[k] = s_all[b * 602 + gs + k];
    float bb[4];
    win_to_box(gs + k, bb);
    bx0[k] = bb[0]; bx1[k] = bb[1]; bx2[k] = bb[2]; bx3[k] = bb[3];
  }
  __syncthreads();
  for (int it = 0; it < nsel; ++it) {
    float bv = -INFINITY;
    int bi = 0x7fffffff;
    for (int k = tid; k < cnt; k += 64) {
      float v = sc[k];
      if (v > bv || (v == bv && k < bi)) { bv = v; bi = k; }
    }
#pragma unroll
    for (int off = 32; off > 0; off >>= 1) {
      float ov = __shfl_down(bv, off);
      int oi = __shfl_down(bi, off);
      if (ov > bv || (ov == bv && oi < bi)) { bv = ov; bi = oi; }
    }
    bi = __shfl(bi, 0);
    if (tid == 0) idx_i[obase + it] = gs + bi;
    float X0 = bx0[bi], X1 = bx1[bi], X2 = bx2[bi], X3 = bx3[bi];
    float a1 = (X2 - X0 + 1.f) * (X3 - X1 + 1.f);
    __syncthreads();
    for (int k = tid; k < cnt; k += 64) {
      float x0 = fmaxf(X0, bx0[k]);
      float y0 = fmaxf(X1, bx1[k]);
      float x1 = fminf(X2, bx2[k]);
      float y1 = fminf(X3, bx3[k]);
      float inter = fmaxf(x1 - x0 + 1.f, 0.f) * fmaxf(y1 - y0 + 1.f, 0.f);
      float a2 = (bx2[k] - bx0[k] + 1.f) * (bx3[k] - bx1[k] + 1.f);
      float iou = inter / (a1 + a2 - inter);
      if (iou > 0.25f) sc[k] = -INFINITY;
    }
    if (tid == 0) sc[bi] = -INFINITY;
    __syncthreads();
  }
}

// ---- gather ---------------------------------------------------------------
__global__ void gather_kernel(const int* __restrict__ idx_i, const float* __restrict__ s_all,
                              float* __restrict__ boxes, float* __restrict__ out) {
  int t = blockIdx.x * blockDim.x + threadIdx.x;
  if (t >= 112) return;
  int b = t / 7;
  int w = idx_i[t];
  out[OFF_IDX + t] = (float)w;
  out[OFF_WSC + t] = s_all[b * 602 + w];
  float bb[4];
  win_to_box(w, bb);
#pragma unroll
  for (int k = 0; k < 4; ++k) {
    boxes[t * 4 + k] = bb[k];
    out[OFF_CRD + t * 4 + k] = bb[k];
  }
}

// ---- bilinear crop-resize 448 -> 112 (fp32, exact) ------------------------
__global__ void crop_resize_kernel(const float* __restrict__ x, const float* __restrict__ boxes,
                                   float* __restrict__ wimgs) {
  int idx = blockIdx.x * blockDim.x + threadIdx.x;
  const int total = 112 * 3 * 112 * 112;
  if (idx >= total) return;
  int j = idx % 112;
  int i = (idx / 112) % 112;
  int ch = (idx / (112 * 112)) % 3;
  int bp = idx / (3 * 112 * 112);
  int b = bp / 7;
  const float* bx = boxes + bp * 4;
  float t_i = (float)i / 111.0f;
  float t_j = (float)j / 111.0f;
  float rs = bx[0] + (bx[2] - bx[0]) * t_i;
  float cs = bx[1] + (bx[3] - bx[1]) * t_j;
  float r0f = floorf(rs), c0f = floorf(cs);
  float wr = rs - r0f, wc = cs - c0f;
  int r0 = (int)r0f, c0 = (int)c0f;
  int r1 = min(r0 + 1, 447), c1 = min(c0 + 1, 447);
  const float* img = x + ((size_t)b * 3 + ch) * 448 * 448;
  float v00 = img[r0 * 448 + c0], v01 = img[r0 * 448 + c1];
  float v10 = img[r1 * 448 + c0], v11 = img[r1 * 448 + c1];
  float top = (1.f - wc) * v00 + wc * v01;
  float bot = (1.f - wc) * v10 + wc * v11;
  wimgs[idx] = (1.f - wr) * top + wr * bot;
}

// ---- zero fill (16B) ------------------------------------------------------
__global__ void zf8_kernel(uint4* __restrict__ p, int n16) {
  int idx = blockIdx.x * blockDim.x + threadIdx.x;
  if (idx < n16) p[idx] = make_uint4(0, 0, 0, 0);
}

// ---- weight packing: wpk[t][co][ci] bf16 from fp32 [co][ci][3][3] ---------
__global__ void packw_kernel(const float* __restrict__ w, __hip_bfloat16* __restrict__ dst,
                             int Cout, int Cin) {
  int idx = blockIdx.x * blockDim.x + threadIdx.x;
  int total = Cout * Cin * 9;
  if (idx >= total) return;
  int ci = idx % Cin;
  int rc = idx / Cin;
  int co = rc % Cout;
  int t = rc / Cout;
  dst[idx] = __float2bfloat16(w[((size_t)co * Cin + ci) * 9 + t]);
}

// ---- L0 weight packing: wpk0[co][32] --------------------------------------
__global__ void packw0_kernel(const float* __restrict__ w, __hip_bfloat16* __restrict__ dst) {
  int idx = blockIdx.x * blockDim.x + threadIdx.x;
  if (idx >= 64 * 32) return;
  int co = idx >> 5, k = idx & 31;
  float v = 0.f;
  if (k < 27) {
    int t = k / 3, c = k - t * 3;
    v = w[((size_t)co * 3 + c) * 9 + t];
  }
  dst[idx] = __float2bfloat16(v);
}

// ---- im2col for Cin=3 layers: A[m][32] bf16 -------------------------------
__global__ void im2col3_kernel(const float* __restrict__ x, __hip_bfloat16* __restrict__ A,
                               int N, int Hin, int Hout) {
  int m = blockIdx.x * blockDim.x + threadIdx.x;
  int total = N * Hout * Hout;
  if (m >= total) return;
  int n = m / (Hout * Hout);
  int rem = m - n * (Hout * Hout);
  int oh = rem / Hout, ow = rem - (rem / Hout) * Hout;
  const float* xb = x + (size_t)n * 3 * Hin * Hin;
  __hip_bfloat16* a = A + (size_t)m * 32;
#pragma unroll
  for (int kh = 0; kh < 3; ++kh) {
#pragma unroll
    for (int kw = 0; kw < 3; ++kw) {
      int ih = 2 * oh + kh, iw = 2 * ow + kw;
      bool ok = (ih < Hin) && (iw < Hin);
#pragma unroll
      for (int c = 0; c < 3; ++c) {
        float v = ok ? xb[(size_t)c * Hin * Hin + (size_t)ih * Hin + iw] : 0.f;
        a[(kh * 3 + kw) * 3 + c] = __float2bfloat16(v);
      }
    }
  }
#pragma unroll
  for (int k = 27; k < 32; ++k) a[k] = __float2bfloat16(0.f);
}

// ================= bf16 MFMA conv (implicit GEMM, NHWC padded) ==============
// IM2COL: 8 waves/block (512 thr), px-only tiling (M huge, blocks plentiful).
// WIDE:   4 waves/block (256 thr) = 2 co-groups x 2 px-groups (64 px/block)
//         -> 2-4x block count of the 8-wave version: latency hidden by TLP.
// K-loop: taps-outer, q in PAIRS (full 128B line consumed while resident).
// blockIdx.z splits q-range (nqz kept even).
template <bool IM2COL, bool WIDE>
__global__ __launch_bounds__(512) void conv_mfma_kernel(
    const __hip_bfloat16* __restrict__ in, const __hip_bfloat16* __restrict__ wpk,
    const float* __restrict__ bias, __hip_bfloat16* __restrict__ outp,
    float* __restrict__ pbuf,
    int M, int Hout, int Wout, int Hp, int Wp, int Cin, int Cout, int pad,
    int Hop, int Wop) {
  const int l = threadIdx.x & 63;
  const int w = threadIdx.x >> 6;
  int px0, co0;
  if (WIDE) {
    px0 = blockIdx.y * 64 + (w & 1) * 32;
    co0 = blockIdx.x * 128 + (w >> 1) * 64;
  } else {
    px0 = blockIdx.y * 256 + w * 32;
    co0 = blockIdx.x * 64;
  }
  if (px0 >= M) return;
  const int half = l >> 4;
  const int lr = l & 15;
  const int HWo = Hout * Wout;

  int mA0 = px0 + lr;      if (mA0 >= M) mA0 = M - 1;
  int mA1 = px0 + 16 + lr; if (mA1 >= M) mA1 = M - 1;
  const __hip_bfloat16* pA0;
  const __hip_bfloat16* pA1;
  if (IM2COL) {
    pA0 = in + (size_t)mA0 * 32 + half * 8;
    pA1 = in + (size_t)mA1 * 32 + half * 8;
  } else {
    int n0 = mA0 / HWo, r0 = mA0 - n0 * HWo, oh0 = r0 / Wout, ow0 = r0 - (r0 / Wout) * Wout;
    int n1 = mA1 / HWo, r1 = mA1 - n1 * HWo, oh1 = r1 / Wout, ow1 = r1 - (r1 / Wout) * Wout;
    pA0 = in + (((size_t)n0 * Hp + (2 * oh0 - pad + 1)) * Wp + (2 * ow0 - pad + 1)) * Cin +
          half * 8;
    pA1 = in + (((size_t)n1 * Hp + (2 * oh1 - pad + 1)) * Wp + (2 * ow1 - pad + 1)) * Cin +
          half * 8;
  }
  const __hip_bfloat16* pB = wpk + (size_t)(co0 + lr) * Cin + half * 8;
  const size_t sCo = (size_t)Cout * Cin;

  f32x4 acc[2][4];
#pragma unroll
  for (int ms = 0; ms < 2; ++ms)
#pragma unroll
    for (int s = 0; s < 4; ++s) acc[ms][s] = (f32x4){0.f, 0.f, 0.f, 0.f};

  const int nq = Cin >> 5;
  const int nqz = nq / gridDim.z;
  const int qlo = blockIdx.z * nqz;
  const int qhi = qlo + nqz;
  if (IM2COL) {
    for (int q = qlo; q < qhi; ++q) {
      short8 a0 = *(const short8*)(pA0);
      short8 a1 = *(const short8*)(pA1);
#pragma unroll
      for (int s = 0; s < 4; ++s) {
        short8 b = *(const short8*)(pB + (size_t)s * 16 * Cin);
        acc[0][s] = __builtin_amdgcn_mfma_f32_16x16x32_bf16(a0, b, acc[0][s], 0, 0, 0);
        acc[1][s] = __builtin_amdgcn_mfma_f32_16x16x32_bf16(a1, b, acc[1][s], 0, 0, 0);
      }
    }
  } else {
    // q in pairs (nqz even for all non-im2col layers/z-splits)
    for (int q = qlo; q < qhi; q += 2) {
      const int qa = q << 5, qb32 = qa + 32;
#pragma unroll
      for (int kh = 0; kh < 3; ++kh) {
#pragma unroll
        for (int kw = 0; kw < 3; ++kw) {
          const int dA = (kh * Wp + kw) * Cin;
          short8 a00 = *(const short8*)(pA0 + dA + qa);
          short8 a01 = *(const short8*)(pA0 + dA + qb32);
          short8 a10 = *(const short8*)(pA1 + dA + qa);
          short8 a11 = *(const short8*)(pA1 + dA + qb32);
          const __hip_bfloat16* qw = pB + (size_t)(kh * 3 + kw) * sCo;
#pragma unroll
          for (int s = 0; s < 4; ++s) {
            short8 b0 = *(const short8*)(qw + (size_t)s * 16 * Cin + qa);
            short8 b1 = *(const short8*)(qw + (size_t)s * 16 * Cin + qb32);
            acc[0][s] = __builtin_amdgcn_mfma_f32_16x16x32_bf16(a00, b0, acc[0][s], 0, 0, 0);
            acc[0][s] = __builtin_amdgcn_mfma_f32_16x16x32_bf16(a01, b1, acc[0][s], 0, 0, 0);
            acc[1][s] = __builtin_amdgcn_mfma_f32_16x16x32_bf16(a10, b0, acc[1][s], 0, 0, 0);
            acc[1][s] = __builtin_amdgcn_mfma_f32_16x16x32_bf16(a11, b1, acc[1][s], 0, 0, 0);
          }
        }
      }
    }
  }

  if (gridDim.z == 1) {
    float bj0 = bias[co0 + lr];
    float bj1 = bias[co0 + 16 + lr];
    float bj2 = bias[co0 + 32 + lr];
    float bj3 = bias[co0 + 48 + lr];
#pragma unroll
    for (int ms = 0; ms < 2; ++ms) {
#pragma unroll
      for (int r = 0; r < 4; ++r) {
        int m = px0 + ms * 16 + half * 4 + r;
        if (m >= M) continue;
        int n = m / HWo, rem = m - n * HWo;
        int oh = rem / Wout, ow = rem - (rem / Wout) * Wout;
        __hip_bfloat16* ob =
            outp + (((size_t)n * Hop + oh + 1) * Wop + (ow + 1)) * Cout + co0 + lr;
        ob[0] = __float2bfloat16(fmaxf(acc[ms][0][r] + bj0, 0.f));
        ob[16] = __float2bfloat16(fmaxf(acc[ms][1][r] + bj1, 0.f));
        ob[32] = __float2bfloat16(fmaxf(acc[ms][2][r] + bj2, 0.f));
        ob[48] = __float2bfloat16(fmaxf(acc[ms][3][r] + bj3, 0.f));
      }
    }
  } else {
    float* pz = pbuf + (size_t)blockIdx.z * M * Cout;
#pragma unroll
    for (int ms = 0; ms < 2; ++ms) {
#pragma unroll
      for (int r = 0; r < 4; ++r) {
        int m = px0 + ms * 16 + half * 4 + r;
        if (m >= M) continue;
        float* pm = pz + (size_t)m * Cout + co0 + lr;
        pm[0] = acc[ms][0][r];
        pm[16] = acc[ms][1][r];
        pm[32] = acc[ms][2][r];
        pm[48] = acc[ms][3][r];
      }
    }
  }
}

// ---- reduce z partials + bias + relu -> padded NHWC bf16 ------------------
__global__ void reduce_nhwc_kernel(const float* __restrict__ pbuf, const float* __restrict__ bias,
                                   __hip_bfloat16* __restrict__ outp, int M, int Cout, int nz,
                                   int Hout, int Wout, int Hop, int Wop) {
  int idx = blockIdx.x * blockDim.x + threadIdx.x;
  if (idx >= M * Cout) return;
  int m = idx / Cout, co = idx - m * Cout;
  float s = 0.f;
  for (int z = 0; z < nz; ++z) s += pbuf[(size_t)z * M * Cout + idx];
  s = fmaxf(s + bias[co], 0.f);
  int HWo = Hout * Wout;
  int n = m / HWo, rem = m - n * HWo;
  int oh = rem / Wout, ow = rem - (rem / Wout) * Wout;
  outp[(((size_t)n * Hop + oh + 1) * Wop + (ow + 1)) * Cout + co] = __float2bfloat16(s);
}

// ---- mean pool over NHWC padded interior ----------------------------------
__global__ void avgpool_nhwc_kernel(const __hip_bfloat16* __restrict__ feat,
                                    float* __restrict__ pooled, int Nimg, int H, int Hp, int C) {
  int idx = blockIdx.x * blockDim.x + threadIdx.x;
  if (idx >= Nimg * C) return;
  int n = idx / C, c = idx - n * C;
  float s = 0.f;
  for (int h = 1; h <= H; ++h)
    for (int ww = 1; ww <= H; ++ww)
      s += __bfloat162float(feat[(((size_t)n * Hp + h) * Hp + ww) * C + c]);
  pooled[idx] = s / (float)(H * H);
}

// ---- head GEMM (fp32) -----------------------------------------------------
__global__ void head_kernel(const float* __restrict__ pooled, const float* __restrict__ hw,
                            const float* __restrict__ hb, float* __restrict__ outp, int M) {
  int idx = blockIdx.x * blockDim.x + threadIdx.x;
  if (idx >= M * 200) return;
  int m = idx / 200, c = idx - m * 200;
  float acc = hb[c];
  const float* pm = pooled + m * 512;
  for (int k = 0; k < 512; ++k) acc = fmaf(pm[k], hw[k * 200 + c], acc);
  outp[idx] = acc;
}

// ---------------------------------------------------------------------------
static void launch_conv(bool im2col, const __hip_bfloat16* in, const __hip_bfloat16* wpk,
                        const float* bv, __hip_bfloat16* dst, float* pbuf, int nz, int M,
                        int Hout, int Hp, int Cin, int Cout, int pad, int Hop, hipStream_t s) {
  if (im2col) {
    dim3 grid(Cout / 64, cdiv(M, 256), nz);
    conv_mfma_kernel<true, false><<<grid, 512, 0, s>>>(in, wpk, bv, dst, pbuf, M, Hout, Hout, Hp,
                                                       Hp, Cin, Cout, pad, Hop, Hop);
  } else {
    dim3 grid(Cout / 128, cdiv(M, 64), nz);  // 4-wave blocks, 64 px each
    conv_mfma_kernel<false, true><<<grid, 256, 0, s>>>(in, wpk, bv, dst, pbuf, M, Hout, Hout, Hp,
                                                       Hp, Cin, Cout, pad, Hop, Hop);
  }
  if (nz > 1)
    reduce_nhwc_kernel<<<cdiv(M * Cout, BS), BS, 0, s>>>(pbuf, bv, dst, M, Cout, nz, Hout, Hout,
                                                         Hop, Hop);
}

static void zf(__hip_bfloat16* p, size_t n, hipStream_t s) {
  zf8_kernel<<<cdiv((int)(n / 8), BS), BS, 0, s>>>((uint4*)p, (int)(n / 8));
}

extern "C" void kernel_launch(void* const* d_in, const int* in_sizes, int n_in,
                              void* d_out, int out_size, void* d_ws, size_t ws_size,
                              hipStream_t stream) {
  const float* x = (const float*)d_in[0];
  const float* att = (const float*)d_in[1];
  const float* W[5] = {(const float*)d_in[2], (const float*)d_in[4], (const float*)d_in[6],
                       (const float*)d_in[8], (const float*)d_in[10]};
  const float* Bv[5] = {(const float*)d_in[3], (const float*)d_in[5], (const float*)d_in[7],
                        (const float*)d_in[9], (const float*)d_in[11]};
  const float* head_w = (const float*)d_in[12];
  const float* head_b = (const float*)d_in[13];
  float* out = (float*)d_out;
  float* ws = (float*)d_ws;

  // ---- workspace (~135MB) ----
  size_t o = 0;
  float* s_all = ws + o;  o += 16 * 602;
  int* idx_i = (int*)(ws + o); o += 112;
  float* boxes = ws + o;  o += 112 * 4;
  float* pooled = ws + o; o += (size_t)112 * 512;
  float* wimgs = ws + o;  o += (size_t)112 * 3 * 112 * 112;
  __hip_bfloat16* hbb = (__hip_bfloat16*)(ws + o);
  size_t h = 0;
  __hip_bfloat16* wpk0 = hbb + h; h += 64 * 32;
  __hip_bfloat16* wpk1 = hbb + h; h += (size_t)9 * 128 * 64;
  __hip_bfloat16* wpk2 = hbb + h; h += (size_t)9 * 256 * 128;
  __hip_bfloat16* wpk3 = hbb + h; h += (size_t)9 * 512 * 256;
  __hip_bfloat16* wpk4 = hbb + h; h += (size_t)9 * 512 * 512;
  __hip_bfloat16* A_L0 = hbb + h; h += (size_t)200704 * 32;          // 6.42M el
  __hip_bfloat16* fL3c = A_L0;                                        // alias: crop-L3 out
  __hip_bfloat16* bufA = hbb + h; h += (size_t)4 * 226 * 226 * 64;   // 13.08M el
  float* pK = (float*)bufA;                                           // alias: split-K partials
  __hip_bfloat16* bufB = hbb + h; h += (size_t)4 * 114 * 114 * 128;  // 6.65M el
  __hip_bfloat16* bufC16 = hbb + h; h += (size_t)16 * 58 * 58 * 256; // 13.78M el
  __hip_bfloat16* fL3b = hbb + h; h += (size_t)16 * 30 * 30 * 512;   // 7.37M el
  __hip_bfloat16* featB = hbb + h; h += (size_t)16 * 16 * 16 * 512;  // 2.10M el
  __hip_bfloat16* featC = hbb + h; h += (size_t)112 * 6 * 6 * 512;   // 2.06M el

  // ---- proposal path (fp32, exact) ----
  winscores_kernel<<<cdiv(16 * 602, BS), BS, 0, stream>>>(att, s_all, out);
  nms_kernel<<<dim3(16, 2), 64, 0, stream>>>(s_all, idx_i);
  gather_kernel<<<1, 128, 0, stream>>>(idx_i, s_all, boxes, out);
  crop_resize_kernel<<<cdiv(112 * 3 * 112 * 112, BS), BS, 0, stream>>>(x, boxes, wimgs);

  // ---- pack weights ----
  packw0_kernel<<<cdiv(64 * 32, BS), BS, 0, stream>>>(W[0], wpk0);
  packw_kernel<<<cdiv(9 * 128 * 64, BS), BS, 0, stream>>>(W[1], wpk1, 128, 64);
  packw_kernel<<<cdiv(9 * 256 * 128, BS), BS, 0, stream>>>(W[2], wpk2, 256, 128);
  packw_kernel<<<cdiv(9 * 512 * 256, BS), BS, 0, stream>>>(W[3], wpk3, 512, 256);
  packw_kernel<<<cdiv(9 * 512 * 512, BS), BS, 0, stream>>>(W[4], wpk4, 512, 512);

  // ---- big encoder: L0-L2 in 4-image chunks; L3, L4 over all 16 ----
  zf(bufA, (size_t)4 * 226 * 226 * 64, stream);
  zf(bufB, (size_t)4 * 114 * 114 * 128, stream);
  zf(bufC16, (size_t)16 * 58 * 58 * 256, stream);
  zf(fL3b, (size_t)16 * 30 * 30 * 512, stream);
  zf(featB, (size_t)16 * 16 * 16 * 512, stream);
  for (int chunk = 0; chunk < 4; ++chunk) {
    int n0 = chunk * 4;
    im2col3_kernel<<<cdiv(200704, BS), BS, 0, stream>>>(x + (size_t)n0 * 3 * 448 * 448, A_L0, 4,
                                                        448, 224);
    launch_conv(true, A_L0, wpk0, Bv[0], bufA, nullptr, 1, 200704, 224, 0, 32, 64, 0, 226,
                stream);
    launch_conv(false, bufA, wpk1, Bv[1], bufB, nullptr, 1, 50176, 112, 226, 64, 128, 0, 114,
                stream);
    launch_conv(false, bufB, wpk2, Bv[2], bufC16 + (size_t)n0 * 58 * 58 * 256, nullptr, 1, 12544,
                56, 114, 128, 256, 0, 58, stream);
  }
  launch_conv(false, bufC16, wpk3, Bv[3], fL3b, nullptr, 1, 12544, 28, 58, 256, 512, 0, 30,
              stream);
  launch_conv(false, fL3b, wpk4, Bv[4], featB, pK, 4, 3136, 14, 30, 512, 512, 0, 16, stream);
  avgpool_nhwc_kernel<<<cdiv(16 * 512, BS), BS, 0, stream>>>(featB, pooled, 16, 14, 16, 512);
  head_kernel<<<cdiv(16 * 200, BS), BS, 0, stream>>>(pooled, head_w, head_b, out + OFF_LAB, 16);

  // ---- crop encoder: L0-L2 in 56-crop chunks; L3, L4 over all 112 ----
  zf(bufA, (size_t)4 * 226 * 226 * 64, stream);
  zf(bufB, (size_t)4 * 114 * 114 * 128, stream);
  zf(bufC16, (size_t)16 * 58 * 58 * 256, stream);
  zf(featC, (size_t)112 * 6 * 6 * 512, stream);
  for (int chunk = 0; chunk < 2; ++chunk) {
    int c0 = chunk * 56;
    im2col3_kernel<<<cdiv(175616, BS), BS, 0, stream>>>(wimgs + (size_t)c0 * 3 * 112 * 112, A_L0,
                                                        56, 112, 56);
    launch_conv(true, A_L0, wpk0, Bv[0], bufA, nullptr, 1, 175616, 56, 0, 32, 64, 0, 58, stream);
    launch_conv(false, bufA, wpk1, Bv[1], bufB, nullptr, 1, 43904, 28, 58, 64, 128, 0, 30,
                stream);
    launch_conv(false, bufB, wpk2, Bv[2], bufC16 + (size_t)c0 * 16 * 16 * 256, nullptr, 1, 10976,
                14, 30, 128, 256, 0, 16, stream);
  }
  // crop-L3 all-112 (z=2, nqz=4 even): fL3c aliases A_L0 (dead after last im2col)
  zf(fL3c, (size_t)112 * 9 * 9 * 512, stream);
  launch_conv(false, bufC16, wpk3, Bv[3], fL3c, pK, 2, 5488, 7, 16, 256, 512, 0, 9, stream);
  // crop-L4 all-112 (z=4, nqz=4 even)
  launch_conv(false, fL3c, wpk4, Bv[4], featC, pK, 4, 1792, 4, 9, 512, 512, 1, 6, stream);
  avgpool_nhwc_kernel<<<cdiv(112 * 512, BS), BS, 0, stream>>>(featC, pooled, 112, 4, 6, 512);
  head_kernel<<<cdiv(112 * 200, BS), BS, 0, stream>>>(pooled, head_w, head_b, out + OFF_LOG, 112);
}